// Round 8
// baseline (235.698 us; speedup 1.0000x reference)
//
#include <hip/hip_runtime.h>

typedef unsigned short u16;
typedef __bf16 bf16x8 __attribute__((ext_vector_type(8)));
typedef float f32x4 __attribute__((ext_vector_type(4)));
typedef unsigned int u32x4 __attribute__((ext_vector_type(4)));
typedef unsigned int u32x2 __attribute__((ext_vector_type(2)));

#define MFMA16(a, b, c) __builtin_amdgcn_mfma_f32_16x16x32_bf16((a), (b), (c), 0, 0, 0)

// RNE fp32 -> bf16
__device__ __forceinline__ u16 f2bf(float f) {
    unsigned u = __builtin_bit_cast(unsigned, f);
    u = u + 0x7FFFu + ((u >> 16) & 1u);
    return (u16)(u >> 16);
}
__device__ __forceinline__ unsigned pk2(float a, float b) {
    return (unsigned)f2bf(a) | ((unsigned)f2bf(b) << 16);
}
__device__ __forceinline__ u32x4 pk8(f32x4 a, f32x4 b) {
    u32x4 r;
    r[0] = pk2(a[0], a[1]); r[1] = pk2(a[2], a[3]);
    r[2] = pk2(b[0], b[1]); r[3] = pk2(b[2], b[3]);
    return r;
}
// single-instruction RNE pack of two fp32 -> bf16x2 (no builtin on gfx950)
__device__ __forceinline__ unsigned cvtpk(float a, float b) {
    unsigned r;
    asm("v_cvt_pk_bf16_f32 %0, %1, %2" : "=v"(r) : "v"(a), "v"(b));
    return r;
}
__device__ __forceinline__ float exp2_fast(float x) {
    float r;
    asm("v_exp_f32 %0, %1" : "=v"(r) : "v"(x));
    return r;
}
__device__ __forceinline__ void lds_load16(const u16* g, u16* l) {
    __builtin_amdgcn_global_load_lds(
        (const __attribute__((address_space(1))) void*)g,
        (__attribute__((address_space(3))) void*)l, 16, 0, 0);
}

#define QSCALE 0.18033688011112042f /* 0.125 * log2(e): softmax in exp2 domain */
#define FIXMAX 13.0f               /* fixed softmax max (exp2 units) */

// ===========================================================================
// Pre-convert all fp32 inputs to bf16 (q,k,v,Wq,Wk,Wv,Wo) into ws, RNE.
// ===========================================================================
__global__ __launch_bounds__(256) void convert_bf16(
    const float* __restrict__ q, const float* __restrict__ k, const float* __restrict__ v,
    const float* __restrict__ Wq, const float* __restrict__ Wk, const float* __restrict__ Wv,
    const float* __restrict__ Wo, u16* __restrict__ dst)
{
    const size_t i = ((size_t)blockIdx.x * 256 + threadIdx.x) * 8;
    const size_t QE = 4194304, WE = 1048576;
    const float* s;
    if (i < QE) s = q + i;
    else if (i < 2 * QE) s = k + (i - QE);
    else if (i < 3 * QE) s = v + (i - 2 * QE);
    else {
        size_t j = i - 3 * QE;
        if (j < WE) s = Wq + j;
        else if (j < 2 * WE) s = Wk + (j - WE);
        else if (j < 3 * WE) s = Wv + (j - 2 * WE);
        else s = Wo + (j - 3 * WE);
    }
    f32x4 a = *(const f32x4*)s;
    f32x4 b = *(const f32x4*)(s + 4);
    *(u32x4*)(dst + i) = pk8(a, b);
}

// ===========================================================================
// bf16 GEMM core v2: 128x128 tile, BK=32, DOUBLE-BUFFERED global_load_lds
// staging with ONE barrier per K-step (attn10's proven pattern), and
// both-sides 16B-unit swizzle so fragment reads are bank-conflict-free:
//   stored unit c of row u holds logical unit c ^ ((u>>1)&3)
//   DMA source pre-swizzled per lane (LDS dest stays linear);
//   reads use quad ^ ((l16>>1)&3)  -> 2 lanes/bank-group (free, m136).
// As/Bs are [2][128*32] u16 (8 KB per half; 32 KB total -> 3 blocks/CU).
// SW=false: acc[mi][ni]=C[m][n], m on (quad,r), n on l16.
// SW=true : swapped operands -> n on (quad,r), m on l16 (V^T epilogue).
// ===========================================================================
template <bool SW>
__device__ __forceinline__ void gemm128_core(
    const u16* __restrict__ A, const u16* __restrict__ B,
    int m0, int n0, u16* As, u16* Bs, int tid, f32x4 acc[4][4])
{
    const int wv = tid >> 6, lane = tid & 63, quad = lane >> 4, l16 = lane & 15;
    const int mh = (wv >> 1) * 64, nh = (wv & 1) * 64;
    // staging: wave wv covers rows [wv*32, wv*32+32); 2 instrs of 16 rows.
    // lane -> row r0 + (lane>>2), stored unit lane&3; source logical unit:
    const int cunit = (lane & 3) ^ ((lane >> 3) & 3);
    const int r0 = wv * 32 + (lane >> 2);
    const u16* gA = A + (size_t)(m0 + r0) * 1024 + cunit * 8;
    const u16* gB = B + (size_t)(n0 + r0) * 1024 + cunit * 8;
    const int xsw = (l16 >> 1) & 3;   // read-side unit XOR ((row>>1)&3)

    // prologue: stage tile 0 into buffer 0
    lds_load16(gA, &As[wv * 1024]);
    lds_load16(gA + 16 * 1024, &As[wv * 1024 + 512]);
    lds_load16(gB, &Bs[wv * 1024]);
    lds_load16(gB + 16 * 1024, &Bs[wv * 1024 + 512]);

    for (int t = 0; t < 32; t++) {
        const int bi = t & 1;
        __syncthreads();  // vmcnt: DMA(t) landed; lgkm: t-1 frag reads done

        if (t < 31) {     // DMA next tile into other buffer; in flight
            const int k0 = (t + 1) * 32;
            const int nb = bi ^ 1;
            lds_load16(gA + k0, &As[nb * 4096 + wv * 1024]);
            lds_load16(gA + 16 * 1024 + k0, &As[nb * 4096 + wv * 1024 + 512]);
            lds_load16(gB + k0, &Bs[nb * 4096 + wv * 1024]);
            lds_load16(gB + 16 * 1024 + k0, &Bs[nb * 4096 + wv * 1024 + 512]);
        }

        const u16* Ab = &As[bi * 4096];
        const u16* Bb = &Bs[bi * 4096];
        bf16x8 af[4], bfr[4];
        #pragma unroll
        for (int mi = 0; mi < 4; mi++)
            af[mi] = *(const bf16x8*)&Ab[(mh + mi * 16 + l16) * 32 + ((quad ^ xsw) << 3)];
        #pragma unroll
        for (int ni = 0; ni < 4; ni++)
            bfr[ni] = *(const bf16x8*)&Bb[(nh + ni * 16 + l16) * 32 + ((quad ^ xsw) << 3)];
        #pragma unroll
        for (int mi = 0; mi < 4; mi++)
            #pragma unroll
            for (int ni = 0; ni < 4; ni++)
                acc[mi][ni] = SW ? MFMA16(bfr[ni], af[mi], acc[mi][ni])
                                 : MFMA16(af[mi], bfr[ni], acc[mi][ni]);
    }
}

// fused QKV projection (bf16 inputs). Q epilogue folds 0.125*log2e.
// Q,K -> [b,h,l,d]; V -> [b,h,d,l] via swapped-operand MFMA (output already
// transposed; 32B-coalesced stores, no LDS transpose). XCD y-strip swizzle.
__global__ __launch_bounds__(256) void qkv_bf(
    const u16* __restrict__ qb, const u16* __restrict__ kb, const u16* __restrict__ vb,
    const u16* __restrict__ wq, const u16* __restrict__ wk, const u16* __restrict__ wvv,
    const float* __restrict__ bq, const float* __restrict__ bk, const float* __restrict__ bv,
    u16* __restrict__ Qh, u16* __restrict__ Kh, u16* __restrict__ Vt)
{
    __shared__ alignas(16) u16 As[2 * 4096];
    __shared__ alignas(16) u16 Bs[2 * 4096];
    const int z = blockIdx.z;
    const u16* A = (z == 0) ? qb : (z == 1) ? kb : vb;
    const u16* B = (z == 0) ? wq : (z == 1) ? wk : wvv;
    const float* bias = (z == 0) ? bq : (z == 1) ? bk : bv;
    const int tid = threadIdx.x;
    const int id = blockIdx.x + (blockIdx.y << 3);
    const int xd = id >> 5;
    const int yd = ((id & 7) << 2) | ((id >> 3) & 3);
    const int m0 = yd * 128, n0 = xd * 128;
    const int wv = tid >> 6, lane = tid & 63, quad = lane >> 4, l16 = lane & 15;
    const int mh = (wv >> 1) * 64, nh = (wv & 1) * 64;

    f32x4 acc[4][4];
    #pragma unroll
    for (int i = 0; i < 4; i++)
        #pragma unroll
        for (int j = 0; j < 4; j++) acc[i][j] = (f32x4){0.f, 0.f, 0.f, 0.f};

    if (z == 2) gemm128_core<true>(A, B, m0, n0, As, Bs, tid, acc);
    else        gemm128_core<false>(A, B, m0, n0, As, Bs, tid, acc);

    if (z < 2) {
        const float scl = (z == 0) ? QSCALE : 1.0f;
        u16* outp = (z == 0) ? Qh : Kh;
        #pragma unroll
        for (int ni = 0; ni < 4; ni++) {
            const int n = n0 + nh + ni * 16 + l16;
            const float bval = bias[n];
            const int h = n >> 6, d = n & 63;
            #pragma unroll
            for (int mi = 0; mi < 4; mi++) {
                const int mbase = m0 + mh + mi * 16 + quad * 4;
                #pragma unroll
                for (int r = 0; r < 4; r++) {
                    const int m = mbase + r;
                    const int bb = m >> 11, l = m & 2047;
                    const float val = (acc[mi][ni][r] + bval) * scl;
                    outp[(((size_t)(bb * 16 + h) * 2048 + l) << 6) + d] = f2bf(val);
                }
            }
        }
    } else {
        // V^T epilogue (swapped-operand acc): element [n][m] with
        // n = n0+nh+ni*16+quad*4+r (head h, dim d), m = m0+mh+mi*16+l16 (l).
        // Stores: fixed (ni,r,mi) -> 16 lanes contiguous 32B.
        const int mW = m0 + mh;
        const int bb = mW >> 11;
        const int l0 = mW & 2047;
        #pragma unroll
        for (int ni = 0; ni < 4; ni++) {
            const int nb = n0 + nh + ni * 16 + quad * 4;
            const f32x4 bv4 = *(const f32x4*)&bias[nb];
            const int h = nb >> 6, d0 = nb & 63;
            u16* vrow = Vt + ((size_t)(bb * 16 + h) * 64 + d0) * 2048;
            #pragma unroll
            for (int mi = 0; mi < 4; mi++) {
                const int l = l0 + mi * 16 + l16;
                #pragma unroll
                for (int r = 0; r < 4; r++)
                    vrow[(size_t)r * 2048 + l] = f2bf(acc[mi][ni][r] + bv4[r]);
            }
        }
    }
}

// output projection (bf16 x bf16 -> fp32 + bias)
__global__ __launch_bounds__(256) void out_bf(
    const u16* __restrict__ Ob, const u16* __restrict__ wo,
    const float* __restrict__ bo, float* __restrict__ out)
{
    __shared__ alignas(16) u16 As[2 * 4096];
    __shared__ alignas(16) u16 Bs[2 * 4096];
    const int tid = threadIdx.x;
    const int id = blockIdx.x + (blockIdx.y << 3);
    const int xd = id >> 5;
    const int yd = ((id & 7) << 2) | ((id >> 3) & 3);
    const int m0 = yd * 128, n0 = xd * 128;
    const int wv = tid >> 6, lane = tid & 63, quad = lane >> 4, l16 = lane & 15;
    const int mh = (wv >> 1) * 64, nh = (wv & 1) * 64;

    f32x4 acc[4][4];
    #pragma unroll
    for (int i = 0; i < 4; i++)
        #pragma unroll
        for (int j = 0; j < 4; j++) acc[i][j] = (f32x4){0.f, 0.f, 0.f, 0.f};

    gemm128_core<false>(Ob, wo, m0, n0, As, Bs, tid, acc);

    #pragma unroll
    for (int ni = 0; ni < 4; ni++) {
        const int n = n0 + nh + ni * 16 + l16;
        const float bval = bo[n];
        #pragma unroll
        for (int mi = 0; mi < 4; mi++) {
            const int mbase = m0 + mh + mi * 16 + quad * 4;
            #pragma unroll
            for (int r = 0; r < 4; r++)
                out[(size_t)(mbase + r) * 1024 + n] = acc[mi][ni][r] + bval;
        }
    }
}

// ===========================================================================
// Flash attention attn10 (proven best, 47.0 us): DMA (global_load_lds) K/V
// staging; linear pitch-64 LDS dest + inverse-swizzled GLOBAL source +
// XOR-swizzled fragment reads; sigma key-permutation in the DMA source
// (register-resident P); mask bias as MFMA C-init; ones-MFMA row sums;
// setprio around MFMA clusters. 1 barrier/chunk.
// ===========================================================================
__global__ __launch_bounds__(256) void attn10(
    const u16* __restrict__ Qh, const u16* __restrict__ Kh,
    const u16* __restrict__ Vt, const int* __restrict__ mask,
    u16* __restrict__ Ob)
{
    __shared__ alignas(16) u16 Ks[2][64 * 64];
    __shared__ alignas(16) u16 Vs[2][64 * 64];
    __shared__ alignas(16) float Ms[2][64];

    const int tid = threadIdx.x;
    const int blk = blockIdx.x;
    const int bh = blk & 31, qt = blk >> 5;       // same-head blocks -> same XCD
    const int b = bh >> 4, h = bh & 15;
    const int wv = tid >> 6, lane = tid & 63, quad = lane >> 4, l16 = lane & 15;

    const int qbase = qt * 128 + wv * 32;
    const u16* Qb = Qh + ((size_t)bh * 2048 + qbase) * 64;
    bf16x8 qf[2][2];
    #pragma unroll
    for (int sub = 0; sub < 2; sub++)
        #pragma unroll
        for (int hf = 0; hf < 2; hf++)
            qf[sub][hf] = *(const bf16x8*)(Qb + (sub * 16 + l16) * 64 + hf * 32 + quad * 8);

    // all-ones B fragment for row-sum MFMA (bf16 1.0 = 0x3F80)
    const u32x4 onebits = {0x3F803F80u, 0x3F803F80u, 0x3F803F80u, 0x3F803F80u};
    const bf16x8 onesf = __builtin_bit_cast(bf16x8, onebits);

    const u16* Kb = Kh + (size_t)bh * 2048 * 64;
    const u16* Vb = Vt + (size_t)bh * 64 * 2048;
    const int* mb = mask + b * 2048;

    // --- DMA staging lane constants ---
    const int urow = lane >> 3;               // 0..7 == u&7
    const int cunit = (lane & 7) ^ urow;      // logical 16B col-unit to fetch
    const int u0 = wv * 16 + urow, u1 = u0 + 8;
    // K LDS row u holds key sigma^-1(u) (register-P layout):
    const int ki0 = (u0 & 3) | (((u0 >> 4) & 1) << 2) | (((u0 >> 2) & 3) << 3) | ((u0 >> 5) << 5);
    const int ki1 = (u1 & 3) | (((u1 >> 4) & 1) << 2) | (((u1 >> 2) & 3) << 3) | ((u1 >> 5) << 5);
    const u16* gk0 = Kb + (size_t)ki0 * 64 + cunit * 8;   // += off*64 per chunk
    const u16* gk1 = Kb + (size_t)ki1 * 64 + cunit * 8;
    const u16* gv0 = Vb + (size_t)u0 * 2048 + cunit * 8;  // += off per chunk
    const u16* gv1 = Vb + (size_t)u1 * 2048 + cunit * 8;

    // prologue: DMA chunk 0 into buf 0; mask regs for chunk 0
    lds_load16(gk0, &Ks[0][wv * 1024]);
    lds_load16(gk1, &Ks[0][wv * 1024 + 512]);
    lds_load16(gv0, &Vs[0][wv * 1024]);
    lds_load16(gv1, &Vs[0][wv * 1024 + 512]);
    float rm = (tid < 64) ? (mb[tid] ? -1e30f : -FIXMAX) : 0.f;

    f32x4 o[2][4];
    #pragma unroll
    for (int sub = 0; sub < 2; sub++)
        #pragma unroll
        for (int db = 0; db < 4; db++) o[sub][db] = (f32x4){0.f, 0.f, 0.f, 0.f};
    f32x4 accL[2];
    accL[0] = (f32x4){0.f, 0.f, 0.f, 0.f};
    accL[1] = (f32x4){0.f, 0.f, 0.f, 0.f};

    const int x0 = l16 & 7;   // read-side XOR (row&7)

    for (int kc = 0; kc < 32; kc++) {
        const int bi = kc & 1;
        if (tid < 64) Ms[bi][tid] = rm;
        __syncthreads();   // drains lgkm (frag reads, Ms) + vmcnt (DMA, rm)

        if (kc < 31) {  // DMA next chunk into the other buffer; in flight
            const int off = (kc + 1) * 64;
            const int nbi = bi ^ 1;
            lds_load16(gk0 + (size_t)off * 64, &Ks[nbi][wv * 1024]);
            lds_load16(gk1 + (size_t)off * 64, &Ks[nbi][wv * 1024 + 512]);
            lds_load16(gv0 + off, &Vs[nbi][wv * 1024]);
            lds_load16(gv1 + off, &Vs[nbi][wv * 1024 + 512]);
            rm = (tid < 64) ? (mb[off + tid] ? -1e30f : -FIXMAX) : 0.f;
        }

        const u16* KsB = Ks[bi];
        const u16* VsB = Vs[bi];

        // S^T = K.Q^T with C-init = mask bias; K frags read once, shared
        // by both subs. st[sub][nb][r] = key 32(nb>>1)+8quad+4(nb&1)+r, q=l16.
        f32x4 st[2][4];
        __builtin_amdgcn_s_setprio(1);
        #pragma unroll
        for (int nb = 0; nb < 4; nb++) {
            const f32x4 mneg = *(const f32x4*)&Ms[bi][((nb >> 1) << 5) + (quad << 3) + ((nb & 1) << 2)];
            const bf16x8 kf0 = *(const bf16x8*)&KsB[(nb * 16 + l16) * 64 + ((quad ^ x0) << 3)];
            const bf16x8 kf1 = *(const bf16x8*)&KsB[(nb * 16 + l16) * 64 + (((4 | quad) ^ x0) << 3)];
            #pragma unroll
            for (int sub = 0; sub < 2; sub++) {
                f32x4 z = mneg;
                z = MFMA16(kf0, qf[sub][0], z);
                z = MFMA16(kf1, qf[sub][1], z);
                st[sub][nb] = z;
            }
        }
        __builtin_amdgcn_s_setprio(0);

        // softmax numerator + in-register P pack (A-frag key order by sigma)
        bf16x8 pf[2][2];
        #pragma unroll
        for (int sub = 0; sub < 2; sub++) {
            #pragma unroll
            for (int nb = 0; nb < 4; nb++)
                #pragma unroll
                for (int r = 0; r < 4; r++) st[sub][nb][r] = exp2_fast(st[sub][nb][r]);
            u32x4 w0, w1;
            w0[0] = cvtpk(st[sub][0][0], st[sub][0][1]);
            w0[1] = cvtpk(st[sub][0][2], st[sub][0][3]);
            w0[2] = cvtpk(st[sub][1][0], st[sub][1][1]);
            w0[3] = cvtpk(st[sub][1][2], st[sub][1][3]);
            w1[0] = cvtpk(st[sub][2][0], st[sub][2][1]);
            w1[1] = cvtpk(st[sub][2][2], st[sub][2][3]);
            w1[2] = cvtpk(st[sub][3][0], st[sub][3][1]);
            w1[3] = cvtpk(st[sub][3][2], st[sub][3][3]);
            pf[sub][0] = __builtin_bit_cast(bf16x8, w0);
            pf[sub][1] = __builtin_bit_cast(bf16x8, w1);
        }

        // PV: V frags read once, shared by both subs
        __builtin_amdgcn_s_setprio(1);
        #pragma unroll
        for (int db = 0; db < 4; db++) {
            const bf16x8 vf0 = *(const bf16x8*)&VsB[(db * 16 + l16) * 64 + ((quad ^ x0) << 3)];
            const bf16x8 vf1 = *(const bf16x8*)&VsB[(db * 16 + l16) * 64 + (((4 | quad) ^ x0) << 3)];
            #pragma unroll
            for (int sub = 0; sub < 2; sub++) {
                o[sub][db] = MFMA16(pf[sub][0], vf0, o[sub][db]);
                o[sub][db] = MFMA16(pf[sub][1], vf1, o[sub][db]);
            }
        }
        // row sums: L += P . 1^T  (accL rows = (quad,r) = same layout as o)
        #pragma unroll
        for (int sub = 0; sub < 2; sub++) {
            accL[sub] = MFMA16(pf[sub][0], onesf, accL[sub]);
            accL[sub] = MFMA16(pf[sub][1], onesf, accL[sub]);
        }
        __builtin_amdgcn_s_setprio(0);
        asm volatile("" ::: "memory");
    }

    #pragma unroll
    for (int sub = 0; sub < 2; sub++) {
        #pragma unroll
        for (int r = 0; r < 4; r++) {
            const float lr = __builtin_amdgcn_rcpf(accL[sub][r]);
            const int qrow = qt * 128 + wv * 32 + sub * 16 + quad * 4 + r;
            #pragma unroll
            for (int db = 0; db < 4; db++)
                Ob[((size_t)(b * 2048 + qrow)) * 1024 + h * 64 + db * 16 + l16] =
                    f2bf(o[sub][db][r] * lr);
        }
    }
}

// ===========================================================================
// FALLBACK path (small ws): fp32-input GEMMs with in-loop conversion.
// ===========================================================================
__global__ __launch_bounds__(256) void qkv_gemm(
    const float* __restrict__ q, const float* __restrict__ k, const float* __restrict__ v,
    const float* __restrict__ Wq, const float* __restrict__ Wk, const float* __restrict__ Wv,
    const float* __restrict__ bq, const float* __restrict__ bk, const float* __restrict__ bv,
    u16* __restrict__ Qh, u16* __restrict__ Kh, u16* __restrict__ Vt)
{
    __shared__ alignas(16) u16 As[128 * 40];
    __shared__ alignas(16) u16 Bs[128 * 40];
    const int z = blockIdx.z;
    const float* A    = (z == 0) ? q  : (z == 1) ? k  : v;
    const float* W    = (z == 0) ? Wq : (z == 1) ? Wk : Wv;
    const float* bias = (z == 0) ? bq : (z == 1) ? bk : bv;
    const int tid = threadIdx.x;
    const int m0 = blockIdx.y * 128, n0 = blockIdx.x * 128;
    const int row = tid >> 1, cseg = tid & 1;
    const float* ga = A + (size_t)(m0 + row) * 1024 + cseg * 16;
    const float* gb = W + (size_t)(n0 + row) * 1024 + cseg * 16;
    const int wv = tid >> 6, lane = tid & 63, quad = lane >> 4, l16 = lane & 15;
    const int mh = (wv >> 1) * 64, nh = (wv & 1) * 64;

    f32x4 acc[4][4];
    for (int i = 0; i < 4; i++)
        for (int j = 0; j < 4; j++) acc[i][j] = (f32x4){0.f, 0.f, 0.f, 0.f};

    f32x4 ra[4], rb[4];
    for (int i = 0; i < 4; i++) {
        ra[i] = *(const f32x4*)(ga + i * 4);
        rb[i] = *(const f32x4*)(gb + i * 4);
    }
    for (int t = 0; t < 32; t++) {
        __syncthreads();
        *(u32x4*)&As[row * 40 + cseg * 16]     = pk8(ra[0], ra[1]);
        *(u32x4*)&As[row * 40 + cseg * 16 + 8] = pk8(ra[2], ra[3]);
        *(u32x4*)&Bs[row * 40 + cseg * 16]     = pk8(rb[0], rb[1]);
        *(u32x4*)&Bs[row * 40 + cseg * 16 + 8] = pk8(rb[2], rb[3]);
        __syncthreads();
        if (t < 31) {
            const int k0 = (t + 1) * 32;
            for (int i = 0; i < 4; i++) {
                ra[i] = *(const f32x4*)(ga + k0 + i * 4);
                rb[i] = *(const f32x4*)(gb + k0 + i * 4);
            }
        }
        bf16x8 af[4], bfr[4];
        for (int mi = 0; mi < 4; mi++)
            af[mi] = *(const bf16x8*)&As[(mh + mi * 16 + l16) * 40 + quad * 8];
        for (int ni = 0; ni < 4; ni++)
            bfr[ni] = *(const bf16x8*)&Bs[(nh + ni * 16 + l16) * 40 + quad * 8];
        for (int mi = 0; mi < 4; mi++)
            for (int ni = 0; ni < 4; ni++)
                acc[mi][ni] = MFMA16(af[mi], bfr[ni], acc[mi][ni]);
    }
    const float scl = (z == 0) ? QSCALE : 1.0f;
    u16* outp = (z == 0) ? Qh : (z == 1) ? Kh : Vt;
    for (int ni = 0; ni < 4; ni++) {
        const int n = n0 + nh + ni * 16 + l16;
        const float bval = bias[n];
        const int h = n >> 6, d = n & 63;
        for (int mi = 0; mi < 4; mi++) {
            const int mbase = m0 + mh + mi * 16 + quad * 4;
            for (int r = 0; r < 4; r++) {
                const int m = mbase + r;
                const int bb = m >> 11, l = m & 2047;
                const float val = (acc[mi][ni][r] + bval) * scl;
                size_t idx;
                if (z < 2) idx = (((size_t)(bb * 16 + h) * 2048 + l) << 6) + d;
                else       idx = (((size_t)(bb * 16 + h) * 64 + d) << 11) + l;
                outp[idx] = f2bf(val);
            }
        }
    }
}

__global__ __launch_bounds__(256) void out_gemm(
    const u16* __restrict__ Ob, const float* __restrict__ Wo,
    const float* __restrict__ bo, float* __restrict__ out)
{
    __shared__ alignas(16) u16 As[128 * 40];
    __shared__ alignas(16) u16 Bs[128 * 40];
    const int tid = threadIdx.x;
    const int m0 = blockIdx.y * 128, n0 = blockIdx.x * 128;
    const int row = tid >> 1, cseg = tid & 1;
    const u16* ga = Ob + (size_t)(m0 + row) * 1024 + cseg * 16;
    const float* gb = Wo + (size_t)(n0 + row) * 1024 + cseg * 16;
    const int wv = tid >> 6, lane = tid & 63, quad = lane >> 4, l16 = lane & 15;
    const int mh = (wv >> 1) * 64, nh = (wv & 1) * 64;

    f32x4 acc[4][4];
    for (int i = 0; i < 4; i++)
        for (int j = 0; j < 4; j++) acc[i][j] = (f32x4){0.f, 0.f, 0.f, 0.f};

    u32x4 ra0 = *(const u32x4*)(ga);
    u32x4 ra1 = *(const u32x4*)(ga + 8);
    f32x4 rb[4];
    for (int i = 0; i < 4; i++) rb[i] = *(const f32x4*)(gb + i * 4);

    for (int t = 0; t < 32; t++) {
        __syncthreads();
        *(u32x4*)&As[row * 40 + cseg * 16]     = ra0;
        *(u32x4*)&As[row * 40 + cseg * 16 + 8] = ra1;
        *(u32x4*)&Bs[row * 40 + cseg * 16]     = pk8(rb[0], rb[1]);
        *(u32x4*)&Bs[row * 40 + cseg * 16 + 8] = pk8(rb[2], rb[3]);
        __syncthreads();
        if (t < 31) {
            const int k0 = (t + 1) * 32;
            ra0 = *(const u32x4*)(ga + k0);
            ra1 = *(const u32x4*)(ga + k0 + 8);
            for (int i = 0; i < 4; i++) rb[i] = *(const f32x4*)(gb + k0 + i * 4);
        }
        bf16x8 af[4], bfr[4];
        for (int mi = 0; mi < 4; mi++)
            af[mi] = *(const bf16x8*)&As[(mh + mi * 16 + l16) * 40 + quad * 8];
        for (int ni = 0; ni < 4; ni++)
            bfr[ni] = *(const bf16x8*)&Bs[(nh + ni * 16 + l16) * 40 + quad * 8];
        for (int mi = 0; mi < 4; mi++)
            for (int ni = 0; ni < 4; ni++)
                acc[mi][ni] = MFMA16(af[mi], bfr[ni], acc[mi][ni]);
    }
    for (int ni = 0; ni < 4; ni++) {
        const int n = n0 + nh + ni * 16 + l16;
        const float bval = bo[n];
        for (int mi = 0; mi < 4; mi++) {
            const int mbase = m0 + mh + mi * 16 + quad * 4;
            for (int r = 0; r < 4; r++)
                out[(size_t)(mbase + r) * 1024 + n] = acc[mi][ni][r] + bval;
        }
    }
}

extern "C" void kernel_launch(void* const* d_in, const int* in_sizes, int n_in,
                              void* d_out, int out_size, void* d_ws, size_t ws_size,
                              hipStream_t stream)
{
    (void)in_sizes; (void)n_in; (void)out_size;
    const float* q  = (const float*)d_in[0];
    const float* k  = (const float*)d_in[1];
    const float* v  = (const float*)d_in[2];
    const int* mask = (const int*)d_in[3];
    const float* Wq = (const float*)d_in[4];
    const float* bq = (const float*)d_in[5];
    const float* Wk = (const float*)d_in[6];
    const float* bk = (const float*)d_in[7];
    const float* Wv = (const float*)d_in[8];
    const float* bv = (const float*)d_in[9];
    const float* Wo = (const float*)d_in[10];
    const float* bo = (const float*)d_in[11];
    float* out = (float*)d_out;

    u16* ws = (u16*)d_ws;
    const size_t QE = 4194304, WE = 1048576;
    const size_t NEED = (6 * QE + 4 * WE) * 2;  // 58,720,256 bytes

    if (ws_size >= NEED) {
        u16* qbf = ws;
        u16* kbf = ws + QE;
        u16* vbf = ws + 2 * QE;
        u16* wqb = ws + 3 * QE;
        u16* wkb = wqb + WE;
        u16* wvb = wqb + 2 * WE;
        u16* wob = wqb + 3 * WE;
        u16* Qh  = ws + 3 * QE + 4 * WE;
        u16* Kh  = Qh + QE;
        u16* Vth = Qh + 2 * QE;
        u16* Obp = qbf;  // qbf dead after qkv_bf; alias
        convert_bf16<<<dim3(8192), 256, 0, stream>>>(q, k, v, Wq, Wk, Wv, Wo, ws);
        qkv_bf<<<dim3(8, 32, 3), 256, 0, stream>>>(qbf, kbf, vbf, wqb, wkb, wvb,
                                                   bq, bk, bv, Qh, Kh, Vth);
        attn10<<<dim3(512), 256, 0, stream>>>(Qh, Kh, Vth, mask, Obp);
        out_bf<<<dim3(8, 32), 256, 0, stream>>>(Obp, wob, bo, out);
    } else {
        u16* Qh  = ws;
        u16* Kh  = ws + QE;
        u16* Vth = ws + 2 * QE;
        u16* Obp = ws + 3 * QE;
        qkv_gemm<<<dim3(8, 32, 3), 256, 0, stream>>>(q, k, v, Wq, Wk, Wv,
                                                     bq, bk, bv, Qh, Kh, Vth);
        attn10<<<dim3(512), 256, 0, stream>>>(Qh, Kh, Vth, mask, Obp);
        out_gemm<<<dim3(8, 32), 256, 0, stream>>>(Obp, Wo, bo, out);
    }
}

// Round 9
// 218.488 us; speedup vs baseline: 1.0788x; 1.0788x over previous
//
#include <hip/hip_runtime.h>

typedef unsigned short u16;
typedef __bf16 bf16x8 __attribute__((ext_vector_type(8)));
typedef float f32x4 __attribute__((ext_vector_type(4)));
typedef unsigned int u32x4 __attribute__((ext_vector_type(4)));
typedef unsigned int u32x2 __attribute__((ext_vector_type(2)));

#define MFMA16(a, b, c) __builtin_amdgcn_mfma_f32_16x16x32_bf16((a), (b), (c), 0, 0, 0)

// RNE fp32 -> bf16
__device__ __forceinline__ u16 f2bf(float f) {
    unsigned u = __builtin_bit_cast(unsigned, f);
    u = u + 0x7FFFu + ((u >> 16) & 1u);
    return (u16)(u >> 16);
}
__device__ __forceinline__ unsigned pk2(float a, float b) {
    return (unsigned)f2bf(a) | ((unsigned)f2bf(b) << 16);
}
__device__ __forceinline__ u32x4 pk8(f32x4 a, f32x4 b) {
    u32x4 r;
    r[0] = pk2(a[0], a[1]); r[1] = pk2(a[2], a[3]);
    r[2] = pk2(b[0], b[1]); r[3] = pk2(b[2], b[3]);
    return r;
}
// single-instruction RNE pack of two fp32 -> bf16x2 (no builtin on gfx950)
__device__ __forceinline__ unsigned cvtpk(float a, float b) {
    unsigned r;
    asm("v_cvt_pk_bf16_f32 %0, %1, %2" : "=v"(r) : "v"(a), "v"(b));
    return r;
}
__device__ __forceinline__ float exp2_fast(float x) {
    float r;
    asm("v_exp_f32 %0, %1" : "=v"(r) : "v"(x));
    return r;
}
__device__ __forceinline__ void lds_load16(const u16* g, u16* l) {
    __builtin_amdgcn_global_load_lds(
        (const __attribute__((address_space(1))) void*)g,
        (__attribute__((address_space(3))) void*)l, 16, 0, 0);
}

#define QSCALE 0.18033688011112042f /* 0.125 * log2(e): softmax in exp2 domain */
#define FIXMAX 13.0f               /* fixed softmax max (exp2 units) */

// ===========================================================================
// Pre-convert all fp32 inputs to bf16 (q,k,v,Wq,Wk,Wv,Wo) into ws, RNE.
// ===========================================================================
__global__ __launch_bounds__(256) void convert_bf16(
    const float* __restrict__ q, const float* __restrict__ k, const float* __restrict__ v,
    const float* __restrict__ Wq, const float* __restrict__ Wk, const float* __restrict__ Wv,
    const float* __restrict__ Wo, u16* __restrict__ dst)
{
    const size_t i = ((size_t)blockIdx.x * 256 + threadIdx.x) * 8;
    const size_t QE = 4194304, WE = 1048576;
    const float* s;
    if (i < QE) s = q + i;
    else if (i < 2 * QE) s = k + (i - QE);
    else if (i < 3 * QE) s = v + (i - 2 * QE);
    else {
        size_t j = i - 3 * QE;
        if (j < WE) s = Wq + j;
        else if (j < 2 * WE) s = Wk + (j - WE);
        else if (j < 3 * WE) s = Wv + (j - 2 * WE);
        else s = Wo + (j - 3 * WE);
    }
    f32x4 a = *(const f32x4*)s;
    f32x4 b = *(const f32x4*)(s + 4);
    *(u32x4*)(dst + i) = pk8(a, b);
}

// ===========================================================================
// bf16 GEMM core (round-3 proven best): 128x128 tile, BK=32, global_load_lds
// width-16 staging, single-buffered 2-barrier loop.
// ===========================================================================
__device__ __forceinline__ void gemm128_core(
    const u16* __restrict__ A, const u16* __restrict__ B,
    int m0, int n0, u16* As, u16* Bs, int tid, f32x4 acc[4][4])
{
    const int wv = tid >> 6, lane = tid & 63, quad = lane >> 4, l16 = lane & 15;
    const int mh = (wv >> 1) * 64, nh = (wv & 1) * 64;
    const int segA0 = wv * 128 + lane;
    const int segA1 = wv * 128 + 64 + lane;
    const int ra0 = segA0 >> 2, ca0 = (segA0 & 3) * 8;
    const int ra1 = segA1 >> 2, ca1 = (segA1 & 3) * 8;
    u16* ldsA0 = &As[(wv * 128) * 8];
    u16* ldsA1 = &As[(wv * 128 + 64) * 8];
    u16* ldsB0 = &Bs[(wv * 128) * 8];
    u16* ldsB1 = &Bs[(wv * 128 + 64) * 8];
    const u16* gA = A + (size_t)m0 * 1024;
    const u16* gB = B + (size_t)n0 * 1024;

    for (int t = 0; t < 32; t++) {
        const int k0 = t * 32;
        __syncthreads();
        lds_load16(gA + (size_t)ra0 * 1024 + k0 + ca0, ldsA0);
        lds_load16(gA + (size_t)ra1 * 1024 + k0 + ca1, ldsA1);
        lds_load16(gB + (size_t)ra0 * 1024 + k0 + ca0, ldsB0);
        lds_load16(gB + (size_t)ra1 * 1024 + k0 + ca1, ldsB1);
        __syncthreads();
        bf16x8 af[4], bfr[4];
        #pragma unroll
        for (int mi = 0; mi < 4; mi++)
            af[mi] = *(const bf16x8*)&As[(mh + mi * 16 + l16) * 32 + quad * 8];
        #pragma unroll
        for (int ni = 0; ni < 4; ni++)
            bfr[ni] = *(const bf16x8*)&Bs[(nh + ni * 16 + l16) * 32 + quad * 8];
        #pragma unroll
        for (int mi = 0; mi < 4; mi++)
            #pragma unroll
            for (int ni = 0; ni < 4; ni++)
                acc[mi][ni] = MFMA16(af[mi], bfr[ni], acc[mi][ni]);
    }
}

// fused QKV projection (bf16 inputs). Q epilogue folds 0.125*log2e.
// Q,K -> [b,h,l,d]; V -> [b,h,d,l]. XCD y-strip swizzle. (round-3 exact)
__global__ __launch_bounds__(256) void qkv_bf(
    const u16* __restrict__ qb, const u16* __restrict__ kb, const u16* __restrict__ vb,
    const u16* __restrict__ wq, const u16* __restrict__ wk, const u16* __restrict__ wvv,
    const float* __restrict__ bq, const float* __restrict__ bk, const float* __restrict__ bv,
    u16* __restrict__ Qh, u16* __restrict__ Kh, u16* __restrict__ Vt)
{
    __shared__ alignas(16) u16 As[128 * 32];
    __shared__ alignas(16) u16 Bs[128 * 32];
    const int z = blockIdx.z;
    const u16* A = (z == 0) ? qb : (z == 1) ? kb : vb;
    const u16* B = (z == 0) ? wq : (z == 1) ? wk : wvv;
    const float* bias = (z == 0) ? bq : (z == 1) ? bk : bv;
    const int tid = threadIdx.x;
    const int id = blockIdx.x + (blockIdx.y << 3);
    const int xd = id >> 5;
    const int yd = ((id & 7) << 2) | ((id >> 3) & 3);
    const int m0 = yd * 128, n0 = xd * 128;
    const int wv = tid >> 6, lane = tid & 63, quad = lane >> 4, l16 = lane & 15;
    const int mh = (wv >> 1) * 64, nh = (wv & 1) * 64;

    f32x4 acc[4][4];
    #pragma unroll
    for (int i = 0; i < 4; i++)
        #pragma unroll
        for (int j = 0; j < 4; j++) acc[i][j] = (f32x4){0.f, 0.f, 0.f, 0.f};

    gemm128_core(A, B, m0, n0, As, Bs, tid, acc);

    const float scl = (z == 0) ? QSCALE : 1.0f;
    u16* outp = (z == 0) ? Qh : (z == 1) ? Kh : Vt;
    #pragma unroll
    for (int ni = 0; ni < 4; ni++) {
        const int n = n0 + nh + ni * 16 + l16;
        const float bval = bias[n];
        const int h = n >> 6, d = n & 63;
        #pragma unroll
        for (int mi = 0; mi < 4; mi++) {
            const int mbase = m0 + mh + mi * 16 + quad * 4;
            #pragma unroll
            for (int r = 0; r < 4; r++) {
                const int m = mbase + r;
                const int bb = m >> 11, l = m & 2047;
                const float val = (acc[mi][ni][r] + bval) * scl;
                size_t idx;
                if (z < 2) idx = (((size_t)(bb * 16 + h) * 2048 + l) << 6) + d;
                else       idx = (((size_t)(bb * 16 + h) * 64 + d) << 11) + l;
                outp[idx] = f2bf(val);
            }
        }
    }
}

// ===========================================================================
// output projection (bf16 x bf16 -> fp32 + bias), retiled 64x128:
// grid (8,64) = 512 blocks = 2 blocks/CU (was 256 = 1/CU, zero cross-block
// latency hiding). Same r3-proven 2-barrier staging; 12 KB LDS; 8 MFMA/step.
// ===========================================================================
__global__ __launch_bounds__(256) void out_bf(
    const u16* __restrict__ Ob, const u16* __restrict__ wo,
    const float* __restrict__ bo, float* __restrict__ out)
{
    __shared__ alignas(16) u16 As[64 * 32];     // 4 KB
    __shared__ alignas(16) u16 Bs[128 * 32];    // 8 KB
    const int tid = threadIdx.x;
    const int m0 = blockIdx.y * 64, n0 = blockIdx.x * 128;
    const int wv = tid >> 6, lane = tid & 63, quad = lane >> 4, l16 = lane & 15;
    const int nh = wv * 32;                     // wave n-strip (4 x 32 = 128)

    // staging lane constants (r3 pattern): A 256 segs (1 instr), B 512 (2)
    const int segA = wv * 64 + lane;
    const int raA = segA >> 2, caA = (segA & 3) * 8;
    const int segB0 = wv * 128 + lane;
    const int segB1 = wv * 128 + 64 + lane;
    const int rb0 = segB0 >> 2, cb0 = (segB0 & 3) * 8;
    const int rb1 = segB1 >> 2, cb1 = (segB1 & 3) * 8;
    u16* ldsA  = &As[(wv * 64) * 8];
    u16* ldsB0 = &Bs[(wv * 128) * 8];
    u16* ldsB1 = &Bs[(wv * 128 + 64) * 8];
    const u16* gA = Ob + (size_t)m0 * 1024;
    const u16* gB = wo + (size_t)n0 * 1024;

    f32x4 acc[4][2];
    #pragma unroll
    for (int i = 0; i < 4; i++)
        #pragma unroll
        for (int j = 0; j < 2; j++) acc[i][j] = (f32x4){0.f, 0.f, 0.f, 0.f};

    for (int t = 0; t < 32; t++) {
        const int k0 = t * 32;
        __syncthreads();
        lds_load16(gA + (size_t)raA * 1024 + k0 + caA, ldsA);
        lds_load16(gB + (size_t)rb0 * 1024 + k0 + cb0, ldsB0);
        lds_load16(gB + (size_t)rb1 * 1024 + k0 + cb1, ldsB1);
        __syncthreads();
        bf16x8 af[4], bfr[2];
        #pragma unroll
        for (int mi = 0; mi < 4; mi++)
            af[mi] = *(const bf16x8*)&As[(mi * 16 + l16) * 32 + quad * 8];
        #pragma unroll
        for (int ni = 0; ni < 2; ni++)
            bfr[ni] = *(const bf16x8*)&Bs[(nh + ni * 16 + l16) * 32 + quad * 8];
        #pragma unroll
        for (int mi = 0; mi < 4; mi++)
            #pragma unroll
            for (int ni = 0; ni < 2; ni++)
                acc[mi][ni] = MFMA16(af[mi], bfr[ni], acc[mi][ni]);
    }

    #pragma unroll
    for (int ni = 0; ni < 2; ni++) {
        const int n = n0 + nh + ni * 16 + l16;
        const float bval = bo[n];
        #pragma unroll
        for (int mi = 0; mi < 4; mi++) {
            const int mbase = m0 + mi * 16 + quad * 4;
            #pragma unroll
            for (int r = 0; r < 4; r++)
                out[(size_t)(mbase + r) * 1024 + n] = acc[mi][ni][r] + bval;
        }
    }
}

// ===========================================================================
// Flash attention attn10 (proven best, 47.0 us): DMA (global_load_lds) K/V
// staging; linear pitch-64 LDS dest + inverse-swizzled GLOBAL source +
// XOR-swizzled fragment reads; sigma key-permutation in the DMA source
// (register-resident P); mask bias as MFMA C-init; ones-MFMA row sums;
// setprio around MFMA clusters. 1 barrier/chunk.
// ===========================================================================
__global__ __launch_bounds__(256) void attn10(
    const u16* __restrict__ Qh, const u16* __restrict__ Kh,
    const u16* __restrict__ Vt, const int* __restrict__ mask,
    u16* __restrict__ Ob)
{
    __shared__ alignas(16) u16 Ks[2][64 * 64];
    __shared__ alignas(16) u16 Vs[2][64 * 64];
    __shared__ alignas(16) float Ms[2][64];

    const int tid = threadIdx.x;
    const int blk = blockIdx.x;
    const int bh = blk & 31, qt = blk >> 5;       // same-head blocks -> same XCD
    const int b = bh >> 4, h = bh & 15;
    const int wv = tid >> 6, lane = tid & 63, quad = lane >> 4, l16 = lane & 15;

    const int qbase = qt * 128 + wv * 32;
    const u16* Qb = Qh + ((size_t)bh * 2048 + qbase) * 64;
    bf16x8 qf[2][2];
    #pragma unroll
    for (int sub = 0; sub < 2; sub++)
        #pragma unroll
        for (int hf = 0; hf < 2; hf++)
            qf[sub][hf] = *(const bf16x8*)(Qb + (sub * 16 + l16) * 64 + hf * 32 + quad * 8);

    // all-ones B fragment for row-sum MFMA (bf16 1.0 = 0x3F80)
    const u32x4 onebits = {0x3F803F80u, 0x3F803F80u, 0x3F803F80u, 0x3F803F80u};
    const bf16x8 onesf = __builtin_bit_cast(bf16x8, onebits);

    const u16* Kb = Kh + (size_t)bh * 2048 * 64;
    const u16* Vb = Vt + (size_t)bh * 64 * 2048;
    const int* mb = mask + b * 2048;

    // --- DMA staging lane constants ---
    const int urow = lane >> 3;               // 0..7 == u&7
    const int cunit = (lane & 7) ^ urow;      // logical 16B col-unit to fetch
    const int u0 = wv * 16 + urow, u1 = u0 + 8;
    // K LDS row u holds key sigma^-1(u) (register-P layout):
    const int ki0 = (u0 & 3) | (((u0 >> 4) & 1) << 2) | (((u0 >> 2) & 3) << 3) | ((u0 >> 5) << 5);
    const int ki1 = (u1 & 3) | (((u1 >> 4) & 1) << 2) | (((u1 >> 2) & 3) << 3) | ((u1 >> 5) << 5);
    const u16* gk0 = Kb + (size_t)ki0 * 64 + cunit * 8;   // += off*64 per chunk
    const u16* gk1 = Kb + (size_t)ki1 * 64 + cunit * 8;
    const u16* gv0 = Vb + (size_t)u0 * 2048 + cunit * 8;  // += off per chunk
    const u16* gv1 = Vb + (size_t)u1 * 2048 + cunit * 8;

    // prologue: DMA chunk 0 into buf 0; mask regs for chunk 0
    lds_load16(gk0, &Ks[0][wv * 1024]);
    lds_load16(gk1, &Ks[0][wv * 1024 + 512]);
    lds_load16(gv0, &Vs[0][wv * 1024]);
    lds_load16(gv1, &Vs[0][wv * 1024 + 512]);
    float rm = (tid < 64) ? (mb[tid] ? -1e30f : -FIXMAX) : 0.f;

    f32x4 o[2][4];
    #pragma unroll
    for (int sub = 0; sub < 2; sub++)
        #pragma unroll
        for (int db = 0; db < 4; db++) o[sub][db] = (f32x4){0.f, 0.f, 0.f, 0.f};
    f32x4 accL[2];
    accL[0] = (f32x4){0.f, 0.f, 0.f, 0.f};
    accL[1] = (f32x4){0.f, 0.f, 0.f, 0.f};

    const int x0 = l16 & 7;   // read-side XOR (row&7)

    for (int kc = 0; kc < 32; kc++) {
        const int bi = kc & 1;
        if (tid < 64) Ms[bi][tid] = rm;
        __syncthreads();   // drains lgkm (frag reads, Ms) + vmcnt (DMA, rm)

        if (kc < 31) {  // DMA next chunk into the other buffer; in flight
            const int off = (kc + 1) * 64;
            const int nbi = bi ^ 1;
            lds_load16(gk0 + (size_t)off * 64, &Ks[nbi][wv * 1024]);
            lds_load16(gk1 + (size_t)off * 64, &Ks[nbi][wv * 1024 + 512]);
            lds_load16(gv0 + off, &Vs[nbi][wv * 1024]);
            lds_load16(gv1 + off, &Vs[nbi][wv * 1024 + 512]);
            rm = (tid < 64) ? (mb[off + tid] ? -1e30f : -FIXMAX) : 0.f;
        }

        const u16* KsB = Ks[bi];
        const u16* VsB = Vs[bi];

        // S^T = K.Q^T with C-init = mask bias; K frags read once, shared
        // by both subs. st[sub][nb][r] = key 32(nb>>1)+8quad+4(nb&1)+r, q=l16.
        f32x4 st[2][4];
        __builtin_amdgcn_s_setprio(1);
        #pragma unroll
        for (int nb = 0; nb < 4; nb++) {
            const f32x4 mneg = *(const f32x4*)&Ms[bi][((nb >> 1) << 5) + (quad << 3) + ((nb & 1) << 2)];
            const bf16x8 kf0 = *(const bf16x8*)&KsB[(nb * 16 + l16) * 64 + ((quad ^ x0) << 3)];
            const bf16x8 kf1 = *(const bf16x8*)&KsB[(nb * 16 + l16) * 64 + (((4 | quad) ^ x0) << 3)];
            #pragma unroll
            for (int sub = 0; sub < 2; sub++) {
                f32x4 z = mneg;
                z = MFMA16(kf0, qf[sub][0], z);
                z = MFMA16(kf1, qf[sub][1], z);
                st[sub][nb] = z;
            }
        }
        __builtin_amdgcn_s_setprio(0);

        // softmax numerator + in-register P pack (A-frag key order by sigma)
        bf16x8 pf[2][2];
        #pragma unroll
        for (int sub = 0; sub < 2; sub++) {
            #pragma unroll
            for (int nb = 0; nb < 4; nb++)
                #pragma unroll
                for (int r = 0; r < 4; r++) st[sub][nb][r] = exp2_fast(st[sub][nb][r]);
            u32x4 w0, w1;
            w0[0] = cvtpk(st[sub][0][0], st[sub][0][1]);
            w0[1] = cvtpk(st[sub][0][2], st[sub][0][3]);
            w0[2] = cvtpk(st[sub][1][0], st[sub][1][1]);
            w0[3] = cvtpk(st[sub][1][2], st[sub][1][3]);
            w1[0] = cvtpk(st[sub][2][0], st[sub][2][1]);
            w1[1] = cvtpk(st[sub][2][2], st[sub][2][3]);
            w1[2] = cvtpk(st[sub][3][0], st[sub][3][1]);
            w1[3] = cvtpk(st[sub][3][2], st[sub][3][3]);
            pf[sub][0] = __builtin_bit_cast(bf16x8, w0);
            pf[sub][1] = __builtin_bit_cast(bf16x8, w1);
        }

        // PV: V frags read once, shared by both subs
        __builtin_amdgcn_s_setprio(1);
        #pragma unroll
        for (int db = 0; db < 4; db++) {
            const bf16x8 vf0 = *(const bf16x8*)&VsB[(db * 16 + l16) * 64 + ((quad ^ x0) << 3)];
            const bf16x8 vf1 = *(const bf16x8*)&VsB[(db * 16 + l16) * 64 + (((4 | quad) ^ x0) << 3)];
            #pragma unroll
            for (int sub = 0; sub < 2; sub++) {
                o[sub][db] = MFMA16(pf[sub][0], vf0, o[sub][db]);
                o[sub][db] = MFMA16(pf[sub][1], vf1, o[sub][db]);
            }
        }
        // row sums: L += P . 1^T  (accL rows = (quad,r) = same layout as o)
        #pragma unroll
        for (int sub = 0; sub < 2; sub++) {
            accL[sub] = MFMA16(pf[sub][0], onesf, accL[sub]);
            accL[sub] = MFMA16(pf[sub][1], onesf, accL[sub]);
        }
        __builtin_amdgcn_s_setprio(0);
        asm volatile("" ::: "memory");
    }

    #pragma unroll
    for (int sub = 0; sub < 2; sub++) {
        #pragma unroll
        for (int r = 0; r < 4; r++) {
            const float lr = __builtin_amdgcn_rcpf(accL[sub][r]);
            const int qrow = qt * 128 + wv * 32 + sub * 16 + quad * 4 + r;
            #pragma unroll
            for (int db = 0; db < 4; db++)
                Ob[((size_t)(b * 2048 + qrow)) * 1024 + h * 64 + db * 16 + l16] =
                    f2bf(o[sub][db][r] * lr);
        }
    }
}

// ===========================================================================
// FALLBACK path (small ws): fp32-input GEMMs with in-loop conversion.
// ===========================================================================
__global__ __launch_bounds__(256) void qkv_gemm(
    const float* __restrict__ q, const float* __restrict__ k, const float* __restrict__ v,
    const float* __restrict__ Wq, const float* __restrict__ Wk, const float* __restrict__ Wv,
    const float* __restrict__ bq, const float* __restrict__ bk, const float* __restrict__ bv,
    u16* __restrict__ Qh, u16* __restrict__ Kh, u16* __restrict__ Vt)
{
    __shared__ alignas(16) u16 As[128 * 40];
    __shared__ alignas(16) u16 Bs[128 * 40];
    const int z = blockIdx.z;
    const float* A    = (z == 0) ? q  : (z == 1) ? k  : v;
    const float* W    = (z == 0) ? Wq : (z == 1) ? Wk : Wv;
    const float* bias = (z == 0) ? bq : (z == 1) ? bk : bv;
    const int tid = threadIdx.x;
    const int m0 = blockIdx.y * 128, n0 = blockIdx.x * 128;
    const int row = tid >> 1, cseg = tid & 1;
    const float* ga = A + (size_t)(m0 + row) * 1024 + cseg * 16;
    const float* gb = W + (size_t)(n0 + row) * 1024 + cseg * 16;
    const int wv = tid >> 6, lane = tid & 63, quad = lane >> 4, l16 = lane & 15;
    const int mh = (wv >> 1) * 64, nh = (wv & 1) * 64;

    f32x4 acc[4][4];
    for (int i = 0; i < 4; i++)
        for (int j = 0; j < 4; j++) acc[i][j] = (f32x4){0.f, 0.f, 0.f, 0.f};

    f32x4 ra[4], rb[4];
    for (int i = 0; i < 4; i++) {
        ra[i] = *(const f32x4*)(ga + i * 4);
        rb[i] = *(const f32x4*)(gb + i * 4);
    }
    for (int t = 0; t < 32; t++) {
        __syncthreads();
        *(u32x4*)&As[row * 40 + cseg * 16]     = pk8(ra[0], ra[1]);
        *(u32x4*)&As[row * 40 + cseg * 16 + 8] = pk8(ra[2], ra[3]);
        *(u32x4*)&Bs[row * 40 + cseg * 16]     = pk8(rb[0], rb[1]);
        *(u32x4*)&Bs[row * 40 + cseg * 16 + 8] = pk8(rb[2], rb[3]);
        __syncthreads();
        if (t < 31) {
            const int k0 = (t + 1) * 32;
            for (int i = 0; i < 4; i++) {
                ra[i] = *(const f32x4*)(ga + k0 + i * 4);
                rb[i] = *(const f32x4*)(gb + k0 + i * 4);
            }
        }
        bf16x8 af[4], bfr[4];
        for (int mi = 0; mi < 4; mi++)
            af[mi] = *(const bf16x8*)&As[(mh + mi * 16 + l16) * 40 + quad * 8];
        for (int ni = 0; ni < 4; ni++)
            bfr[ni] = *(const bf16x8*)&Bs[(nh + ni * 16 + l16) * 40 + quad * 8];
        for (int mi = 0; mi < 4; mi++)
            for (int ni = 0; ni < 4; ni++)
                acc[mi][ni] = MFMA16(af[mi], bfr[ni], acc[mi][ni]);
    }
    const float scl = (z == 0) ? QSCALE : 1.0f;
    u16* outp = (z == 0) ? Qh : (z == 1) ? Kh : Vt;
    for (int ni = 0; ni < 4; ni++) {
        const int n = n0 + nh + ni * 16 + l16;
        const float bval = bias[n];
        const int h = n >> 6, d = n & 63;
        for (int mi = 0; mi < 4; mi++) {
            const int mbase = m0 + mh + mi * 16 + quad * 4;
            for (int r = 0; r < 4; r++) {
                const int m = mbase + r;
                const int bb = m >> 11, l = m & 2047;
                const float val = (acc[mi][ni][r] + bval) * scl;
                size_t idx;
                if (z < 2) idx = (((size_t)(bb * 16 + h) * 2048 + l) << 6) + d;
                else       idx = (((size_t)(bb * 16 + h) * 64 + d) << 11) + l;
                outp[idx] = f2bf(val);
            }
        }
    }
}

__global__ __launch_bounds__(256) void out_gemm(
    const u16* __restrict__ Ob, const float* __restrict__ Wo,
    const float* __restrict__ bo, float* __restrict__ out)
{
    __shared__ alignas(16) u16 As[128 * 40];
    __shared__ alignas(16) u16 Bs[128 * 40];
    const int tid = threadIdx.x;
    const int m0 = blockIdx.y * 128, n0 = blockIdx.x * 128;
    const int row = tid >> 1, cseg = tid & 1;
    const u16* ga = Ob + (size_t)(m0 + row) * 1024 + cseg * 16;
    const float* gb = Wo + (size_t)(n0 + row) * 1024 + cseg * 16;
    const int wv = tid >> 6, lane = tid & 63, quad = lane >> 4, l16 = lane & 15;
    const int mh = (wv >> 1) * 64, nh = (wv & 1) * 64;

    f32x4 acc[4][4];
    for (int i = 0; i < 4; i++)
        for (int j = 0; j < 4; j++) acc[i][j] = (f32x4){0.f, 0.f, 0.f, 0.f};

    u32x4 ra0 = *(const u32x4*)(ga);
    u32x4 ra1 = *(const u32x4*)(ga + 8);
    f32x4 rb[4];
    for (int i = 0; i < 4; i++) rb[i] = *(const f32x4*)(gb + i * 4);

    for (int t = 0; t < 32; t++) {
        __syncthreads();
        *(u32x4*)&As[row * 40 + cseg * 16]     = ra0;
        *(u32x4*)&As[row * 40 + cseg * 16 + 8] = ra1;
        *(u32x4*)&Bs[row * 40 + cseg * 16]     = pk8(rb[0], rb[1]);
        *(u32x4*)&Bs[row * 40 + cseg * 16 + 8] = pk8(rb[2], rb[3]);
        __syncthreads();
        if (t < 31) {
            const int k0 = (t + 1) * 32;
            ra0 = *(const u32x4*)(ga + k0);
            ra1 = *(const u32x4*)(ga + k0 + 8);
            for (int i = 0; i < 4; i++) rb[i] = *(const f32x4*)(gb + k0 + i * 4);
        }
        bf16x8 af[4], bfr[4];
        for (int mi = 0; mi < 4; mi++)
            af[mi] = *(const bf16x8*)&As[(mh + mi * 16 + l16) * 40 + quad * 8];
        for (int ni = 0; ni < 4; ni++)
            bfr[ni] = *(const bf16x8*)&Bs[(nh + ni * 16 + l16) * 40 + quad * 8];
        for (int mi = 0; mi < 4; mi++)
            for (int ni = 0; ni < 4; ni++)
                acc[mi][ni] = MFMA16(af[mi], bfr[ni], acc[mi][ni]);
    }
    for (int ni = 0; ni < 4; ni++) {
        const int n = n0 + nh + ni * 16 + l16;
        const float bval = bo[n];
        for (int mi = 0; mi < 4; mi++) {
            const int mbase = m0 + mh + mi * 16 + quad * 4;
            for (int r = 0; r < 4; r++)
                out[(size_t)(mbase + r) * 1024 + n] = acc[mi][ni][r] + bval;
        }
    }
}

extern "C" void kernel_launch(void* const* d_in, const int* in_sizes, int n_in,
                              void* d_out, int out_size, void* d_ws, size_t ws_size,
                              hipStream_t stream)
{
    (void)in_sizes; (void)n_in; (void)out_size;
    const float* q  = (const float*)d_in[0];
    const float* k  = (const float*)d_in[1];
    const float* v  = (const float*)d_in[2];
    const int* mask = (const int*)d_in[3];
    const float* Wq = (const float*)d_in[4];
    const float* bq = (const float*)d_in[5];
    const float* Wk = (const float*)d_in[6];
    const float* bk = (const float*)d_in[7];
    const float* Wv = (const float*)d_in[8];
    const float* bv = (const float*)d_in[9];
    const float* Wo = (const float*)d_in[10];
    const float* bo = (const float*)d_in[11];
    float* out = (float*)d_out;

    u16* ws = (u16*)d_ws;
    const size_t QE = 4194304, WE = 1048576;
    const size_t NEED = (6 * QE + 4 * WE) * 2;  // 58,720,256 bytes

    if (ws_size >= NEED) {
        u16* qbf = ws;
        u16* kbf = ws + QE;
        u16* vbf = ws + 2 * QE;
        u16* wqb = ws + 3 * QE;
        u16* wkb = wqb + WE;
        u16* wvb = wqb + 2 * WE;
        u16* wob = wqb + 3 * WE;
        u16* Qh  = ws + 3 * QE + 4 * WE;
        u16* Kh  = Qh + QE;
        u16* Vth = Qh + 2 * QE;
        u16* Obp = qbf;  // qbf dead after qkv_bf; alias
        convert_bf16<<<dim3(8192), 256, 0, stream>>>(q, k, v, Wq, Wk, Wv, Wo, ws);
        qkv_bf<<<dim3(8, 32, 3), 256, 0, stream>>>(qbf, kbf, vbf, wqb, wkb, wvb,
                                                   bq, bk, bv, Qh, Kh, Vth);
        attn10<<<dim3(512), 256, 0, stream>>>(Qh, Kh, Vth, mask, Obp);
        out_bf<<<dim3(8, 64), 256, 0, stream>>>(Obp, wob, bo, out);
    } else {
        u16* Qh  = ws;
        u16* Kh  = ws + QE;
        u16* Vth = ws + 2 * QE;
        u16* Obp = ws + 3 * QE;
        qkv_gemm<<<dim3(8, 32, 3), 256, 0, stream>>>(q, k, v, Wq, Wk, Wv,
                                                     bq, bk, bv, Qh, Kh, Vth);
        attn10<<<dim3(512), 256, 0, stream>>>(Qh, Kh, Vth, mask, Obp);
        out_gemm<<<dim3(8, 32), 256, 0, stream>>>(Obp, Wo, bo, out);
    }
}